// Round 7
// baseline (128.374 us; speedup 1.0000x reference)
//
#include <hip/hip_runtime.h>
#include <math.h>

// Problem constants
#define NB   16
#define NC   64
#define HWs  4096
#define NPS  1024
#define LOG2E 1.44269504088896341f

// ws layout in ushort (bf16 bit patterns)
static constexpr size_t PHI_OFF = (size_t)NB * HWs * 8;            // theta: [b][4096][8]
static constexpr size_t GT_OFF  = PHI_OFF + (size_t)NB * NPS * 8;  // phi:   [b][1024][8]
// gT: [b][32][1024]; total 1,179,648 ushorts = 2.25 MB

typedef short s16x8 __attribute__((ext_vector_type(8)));
typedef float f32x4 __attribute__((ext_vector_type(4)));

#define LD8G(p) (*(const s16x8*)(p))
#define SB()    __builtin_amdgcn_sched_barrier(0)

__device__ inline unsigned short f2bf(float f) {
    unsigned int u = __float_as_uint(f);
    u += 0x7fffu + ((u >> 16) & 1u);          // RNE
    return (unsigned short)(u >> 16);
}
__device__ inline unsigned int pk2(float a, float b) {
    unsigned int ua = __float_as_uint(a); ua += 0x7fffu + ((ua >> 16) & 1u);
    unsigned int ub = __float_as_uint(b); ub += 0x7fffu + ((ub >> 16) & 1u);
    return (ua >> 16) | (ub & 0xffff0000u);
}

// ---------------------------------------------------------------------------
// Kernel 1 (v4 + waves_per_eu pin): half-split blocks. Unchanged this round
// (isolating the k_attn asm-pipeline experiment).
// ---------------------------------------------------------------------------
__global__ __launch_bounds__(256) __attribute__((amdgpu_waves_per_eu(4, 4)))
void k_proj(
    const float* __restrict__ x, const float* __restrict__ Wt,
    const float* __restrict__ Wp, const float* __restrict__ Wg,
    unsigned short* __restrict__ ws)
{
    __shared__ float xs[64 * 128];            // 32 KB

    unsigned short* theta = ws;
    unsigned short* phi   = ws + PHI_OFF;
    unsigned short* gT    = ws + GT_OFF;

    const int tid  = threadIdx.x;
    const int blk  = blockIdx.x;
    const int b    = blk >> 6;
    const int rp   = (blk >> 1) & 31;         // image rows {2rp, 2rp+1}
    const int half = blk & 1;                 // block-uniform -> SGPR

    // ---- stage x[b][ci][rp*128 .. +128) -> xs[ci][0..128) ----
    const float* xsrc = x + (size_t)b * NC * HWs + rp * 128;
#pragma unroll
    for (int i = 0; i < 8; ++i) {
        const int idx = i * 256 + tid;        // 0..2047 float4 slots
        const int ci  = idx >> 5;
        const int f4  = idx & 31;
        float4 v = *(const float4*)(xsrc + (size_t)ci * HWs + f4 * 4);
        *(float4*)(xs + ci * 128 + f4 * 4) = v;
    }
    __syncthreads();

    const int h   = tid & 127;
    // wave-uniform (waves 0,1 -> 0; waves 2,3 -> 1); force to SGPR
    const int sub = __builtin_amdgcn_readfirstlane(tid >> 7);
    const int row = h & 1;
    const int col = h >> 1;
    const int px  = row * 64 + col;

    float a4[4], ag8[8];
#pragma unroll
    for (int j = 0; j < 4; ++j) a4[j] = 0.f;
#pragma unroll
    for (int j = 0; j < 8; ++j) ag8[j] = 0.f;

    const float* W8 = (half ? Wp : Wt) + sub * 4 * NC;   // scalar base
    const float* WG = Wg + (half * 16 + sub * 8) * NC;   // scalar base

#pragma unroll 4
    for (int ci = 0; ci < NC; ++ci) {
        const float xv = xs[ci * 128 + px];   // 2-way bank alias: free
#pragma unroll
        for (int j = 0; j < 4; ++j) a4[j] += W8[j * NC + ci] * xv;    // s_load
#pragma unroll
        for (int j = 0; j < 8; ++j) ag8[j] += WG[j * NC + ci] * xv;   // s_load
    }

    if (half == 0) {
        // theta: unpooled, scaled by log2e; channels sub*4 .. sub*4+4
        const int q = (2 * rp + row) * 64 + col;
        uint2 pkd;
        pkd.x = pk2(a4[0] * LOG2E, a4[1] * LOG2E);
        pkd.y = pk2(a4[2] * LOG2E, a4[3] * LOG2E);
        *(uint2*)(theta + ((size_t)b * HWs + q) * 8 + sub * 4) = pkd;
    } else {
        // phi needs pooling: row pair (h^1) then col pair (h^2), within-wave
#pragma unroll
        for (int j = 0; j < 4; ++j) {
            float v = a4[j];
            v = fmaxf(v, __shfl_xor(v, 1));
            v = fmaxf(v, __shfl_xor(v, 2));
            a4[j] = v;
        }
    }

    // g pooling (both halves)
#pragma unroll
    for (int j = 0; j < 8; ++j) {
        float v = ag8[j];
        v = fmaxf(v, __shfl_xor(v, 1));
        v = fmaxf(v, __shfl_xor(v, 2));
        ag8[j] = v;
    }

    if ((h & 3) == 0) {
        const int ps = rp * 32 + (h >> 2);
        if (half == 1) {
            uint2 pkd;
            pkd.x = pk2(a4[0], a4[1]);
            pkd.y = pk2(a4[2], a4[3]);
            *(uint2*)(phi + ((size_t)b * NPS + ps) * 8 + sub * 4) = pkd;
        }
#pragma unroll
        for (int j = 0; j < 8; ++j) {
            const int c = half * 16 + sub * 8 + j;
            gT[((size_t)b * 32 + c) * NPS + ps] = f2bf(ag8[j]);
        }
    }
}

// ---------------------------------------------------------------------------
// Kernel 2 (v9, resubmit): inline-asm load pipeline with counted vmcnt.
// Round-11 note: round-10 bench died at container level (no pytest/profile
// reached — broker failure signature). Kernel re-audited: address bounds OK
// (max gT offset 65472 <= 65536/b-slab; max phi offset in-bounds), vmcnt
// ledger balanced (12 issue/wait8 prologue; 8 issue/wait8 steady; 4/0 drain),
// SB() after every WAITVM (rule-18), no WAR on asm outputs, uniform barriers.
// Resubmitting byte-identical to get the decisive datapoint.
// v9 theory: v8 VGPR=64 is arithmetically impossible for the intended
// dataflow (64 operand VGPRs live at the SB point alone) — compiler sinks
// prefetches at a level sched_barrier/waves_per_eu don't govern. asm-opaque
// load destinations force the ping-pong live; explicit vmcnt(8) keeps 8
// loads in flight across the MFMA/exp region.
// Checks: VGPR must rise to ~110-128; FETCH_SIZE ~14 MB = spill tripwire.
// Fallback if container fails again: SRSRC buffer_load variant (T8).
// ---------------------------------------------------------------------------
__global__ __launch_bounds__(256) __attribute__((amdgpu_waves_per_eu(4, 4)))
void k_attn(
    const float* __restrict__ x, const float* __restrict__ Wo,
    const float* __restrict__ gamma_p, const unsigned short* __restrict__ ws,
    float* __restrict__ out)
{
    __shared__ __align__(16) unsigned char smem[18432]; // P: 4 waves x 2 bufs x 16 x 72 x 2B; epilogue otile[32][68] f32

    const int tid  = threadIdx.x;
    const int wave = __builtin_amdgcn_readfirstlane(tid >> 6);
    const int lane = tid & 63;
    const int quad = lane >> 4, lr = lane & 15;
    const int blk  = blockIdx.x;
    const int b    = blk >> 6;
    const int q0   = (blk & 63) * 64;

    const unsigned short* th = ws + (size_t)b * HWs * 8;
    const unsigned short* ph = ws + PHI_OFF + (size_t)b * NPS * 8;
    const unsigned short* gp = ws + GT_OFF + (size_t)b * 32 * NPS;
    unsigned short* Pw = (unsigned short*)smem + wave * 2304;   // 2 bufs x [16 q][72 s]

    const s16x8 zf = {0, 0, 0, 0, 0, 0, 0, 0};
    const f32x4 zc = {0.f, 0.f, 0.f, 0.f};

    // theta A-fragment: A[m=q=lr][k=quad*8+j], real k<8 in quad 0
    const s16x8 thA = (quad == 0) ? LD8G(th + (size_t)(q0 + wave * 16 + lr) * 8) : zf;

    f32x4 O[2];
    f32x4 l4;
#pragma unroll
    for (int r = 0; r < 4; ++r) { O[0][r] = 0.f; O[1][r] = 0.f; l4[r] = 0.f; }

    // loop-invariant per-lane byte voffsets (VGPRs)
    const int voff_ph0 = (0 * 16 + lr) * 16;
    const int voff_ph1 = (1 * 16 + lr) * 16;
    const int voff_ph2 = (2 * 16 + lr) * 16;
    const int voff_ph3 = (3 * 16 + lr) * 16;
    const int voff_g00 = ((0 * 16 + lr) * NPS + 0 * 32 + quad * 8) * 2;
    const int voff_g01 = ((1 * 16 + lr) * NPS + 0 * 32 + quad * 8) * 2;
    const int voff_g10 = ((0 * 16 + lr) * NPS + 1 * 32 + quad * 8) * 2;
    const int voff_g11 = ((1 * 16 + lr) * NPS + 1 * 32 + quad * 8) * 2;

    // ping-pong pipeline registers (asm-written: allocator must keep live)
    s16x8 phB_e[4], phB_o[4];
    s16x8 Gf_e[2][2], Gf_o[2][2];

#define GL4(dst, off, base)                                                   \
    asm volatile("global_load_dwordx4 %0, %1, %2"                             \
                 : "=v"(dst) : "v"(off), "s"(base) : "memory")

#define LOADPH_A(dst, baseT)                                                  \
    GL4(dst[0], voff_ph0, baseT); GL4(dst[1], voff_ph1, baseT);               \
    GL4(dst[2], voff_ph2, baseT); GL4(dst[3], voff_ph3, baseT);

#define LOADG_A(dst, baseT)                                                   \
    GL4(dst[0][0], voff_g00, baseT); GL4(dst[0][1], voff_g01, baseT);         \
    GL4(dst[1][0], voff_g10, baseT); GL4(dst[1][1], voff_g11, baseT);

#define WAITVM(n) asm volatile("s_waitcnt vmcnt(" #n ")" ::: "memory")

#define QK(Sv, phB)                                                           \
    _Pragma("unroll")                                                         \
    for (int ss = 0; ss < 4; ++ss)                                            \
        Sv[ss] = __builtin_amdgcn_mfma_f32_16x16x32_bf16(thA, phB[ss], zc, 0, 0, 0);

#define EXPST(Sv, wbuf)                                                       \
    _Pragma("unroll")                                                         \
    for (int ss = 0; ss < 4; ++ss)                                            \
        _Pragma("unroll")                                                     \
        for (int r = 0; r < 4; ++r) {                                         \
            const float p = exp2f(Sv[ss][r]);                                 \
            l4[r] += p;                                                       \
            Pw[(wbuf) + (quad * 4 + r) * 72 + ss * 16 + lr] =                 \
                (unsigned short)(__float_as_uint(p) >> 16);                   \
        }

// Steady-state body: issue G(curT)+ph(curT+1) as asm loads; wait for the
// previous iteration's 8 loads (vmcnt(8) leaves this iteration's 8 in
// flight); QK on phCUR, lagged PV on GfPREV, exp/store to wbuf.
#define BODY(phCUR, GfPREV, GfCUR, phNXT, curT, rbuf, wbuf)                   \
    {                                                                         \
        const unsigned short* gbT  = gp + (size_t)(curT) * 64;                \
        const unsigned short* phT1 = ph + (size_t)((curT) + 1) * 512;         \
        LOADG_A(GfCUR, gbT);                                                  \
        LOADPH_A(phNXT, phT1);                                                \
        const s16x8 Pf0 = *(const s16x8*)(Pw + (rbuf) + lr * 72 + quad * 8);  \
        const s16x8 Pf1 = *(const s16x8*)(Pw + (rbuf) + lr * 72 + 32 + quad * 8); \
        WAITVM(8);                                                            \
        SB();                                                                 \
        f32x4 S[4];                                                           \
        QK(S, phCUR);                                                         \
        _Pragma("unroll")                                                     \
        for (int cs = 0; cs < 2; ++cs)                                        \
            O[cs] = __builtin_amdgcn_mfma_f32_16x16x32_bf16(Pf0, GfPREV[0][cs], O[cs], 0, 0, 0); \
        _Pragma("unroll")                                                     \
        for (int cs = 0; cs < 2; ++cs)                                        \
            O[cs] = __builtin_amdgcn_mfma_f32_16x16x32_bf16(Pf1, GfPREV[1][cs], O[cs], 0, 0, 0); \
        EXPST(S, wbuf);                                                       \
    }

    // ---- prologue: issue ph0, G0, ph1 (12 loads); wait ph0 (vmcnt(8)) ----
    LOADPH_A(phB_e, ph);
    LOADG_A(Gf_e, gp);
    {
        const unsigned short* ph1 = ph + 512;
        LOADPH_A(phB_o, ph1);
    }
    WAITVM(8);
    SB();
    {
        f32x4 S[4];
        QK(S, phB_e);
        EXPST(S, 0);
    }

    // ---- steady state: pairs (t odd, t+1 even), t = 1..13 ----
    for (int t = 1; t < 15; t += 2) {
        BODY(phB_o, Gf_e, Gf_o, phB_e, t,     0,    1152);   // odd:  read buf0, write buf1
        BODY(phB_e, Gf_o, Gf_e, phB_o, t + 1, 1152, 0);      // even: read buf1, write buf0
    }

    // ---- t = 15 (odd; only G15 to issue) ----
    {
        const unsigned short* gb15 = gp + (size_t)15 * 64;
        LOADG_A(Gf_o, gb15);
        const s16x8 Pf0 = *(const s16x8*)(Pw + 0 + lr * 72 + quad * 8);
        const s16x8 Pf1 = *(const s16x8*)(Pw + 0 + lr * 72 + 32 + quad * 8);
        WAITVM(4);   // drain ph15 + G14; G15's 4 loads stay in flight
        SB();
        f32x4 S[4];
        QK(S, phB_o);
#pragma unroll
        for (int cs = 0; cs < 2; ++cs)
            O[cs] = __builtin_amdgcn_mfma_f32_16x16x32_bf16(Pf0, Gf_e[0][cs], O[cs], 0, 0, 0);
#pragma unroll
        for (int cs = 0; cs < 2; ++cs)
            O[cs] = __builtin_amdgcn_mfma_f32_16x16x32_bf16(Pf1, Gf_e[1][cs], O[cs], 0, 0, 0);
        EXPST(S, 1152);
    }

    // ---- drain: PV for tile 15 (P in buf1, Gf_o) ----
    {
        WAITVM(0);
        SB();
        const s16x8 Pf0 = *(const s16x8*)(Pw + 1152 + lr * 72 + quad * 8);
        const s16x8 Pf1 = *(const s16x8*)(Pw + 1152 + lr * 72 + 32 + quad * 8);
#pragma unroll
        for (int cs = 0; cs < 2; ++cs)
            O[cs] = __builtin_amdgcn_mfma_f32_16x16x32_bf16(Pf0, Gf_o[0][cs], O[cs], 0, 0, 0);
#pragma unroll
        for (int cs = 0; cs < 2; ++cs)
            O[cs] = __builtin_amdgcn_mfma_f32_16x16x32_bf16(Pf1, Gf_o[1][cs], O[cs], 0, 0, 0);
    }

    // l: butterfly-sum over the 16-lane s-groups; O rows share the same q map
#pragma unroll
    for (int r = 0; r < 4; ++r) {
        float v = l4[r];
        v += __shfl_xor(v, 1);
        v += __shfl_xor(v, 2);
        v += __shfl_xor(v, 4);
        v += __shfl_xor(v, 8);
        l4[r] = 1.f / v;
    }

    __syncthreads();                          // all waves done with their Pw
    float* otile = (float*)smem;              // [32 c][68 q-stride]
#pragma unroll
    for (int cs = 0; cs < 2; ++cs) {
        f32x4 v;
#pragma unroll
        for (int r = 0; r < 4; ++r) v[r] = O[cs][r] * l4[r];
        *(f32x4*)(otile + (cs * 16 + lr) * 68 + wave * 16 + quad * 4) = v;
    }
    __syncthreads();

    // Wo epilogue + residual: thread = (q = tid&63, oc quarter = tid>>6).
    // otile row -> 32 VGPRs once; per-j Wo rows are contiguous 32-float s_loads.
    const int qq = tid & 63;
    const int quarter = __builtin_amdgcn_readfirstlane(tid >> 6); // SGPR -> s_load Wo
    float ov[32];
#pragma unroll
    for (int c = 0; c < 32; ++c) ov[c] = otile[c * 68 + qq];
    const float gam = gamma_p[0];
#pragma unroll
    for (int j = 0; j < 16; ++j) {
        const float* wrow = Wo + (size_t)(quarter * 16 + j) * 32;  // contiguous
        float a = 0.f;
#pragma unroll
        for (int c = 0; c < 32; ++c) a += wrow[c] * ov[c];         // s_load x16
        const size_t ad = ((size_t)b * NC + quarter * 16 + j) * HWs + q0 + qq;
        out[ad] = gam * a + x[ad];
    }
}

extern "C" void kernel_launch(void* const* d_in, const int* in_sizes, int n_in,
                              void* d_out, int out_size, void* d_ws, size_t ws_size,
                              hipStream_t stream) {
    const float* x     = (const float*)d_in[0];
    const float* Wt    = (const float*)d_in[1];
    const float* Wp    = (const float*)d_in[2];
    const float* Wg    = (const float*)d_in[3];
    const float* Wo    = (const float*)d_in[4];
    const float* gamma = (const float*)d_in[5];
    float* out = (float*)d_out;
    unsigned short* ws = (unsigned short*)d_ws;

    k_proj<<<1024, 256, 0, stream>>>(x, Wt, Wp, Wg, ws);
    k_attn<<<1024, 256, 0, stream>>>(x, Wo, gamma, ws, out);
}